// Round 1
// 634.169 us; speedup vs baseline: 1.0446x; 1.0446x over previous
//
#include <hip/hip_runtime.h>

#define DEV __device__ __forceinline__

typedef __attribute__((ext_vector_type(8))) short short8;
typedef __attribute__((ext_vector_type(4))) float f32x4;

DEV float fast_rcp(float x) { return __builtin_amdgcn_rcpf(x); }
DEV float sigm(float x) { return fast_rcp(1.0f + __expf(-x)); }
DEV float tanhf_fast(float x) { return 1.0f - 2.0f * fast_rcp(1.0f + __expf(2.0f * x)); }

DEV short f2bf(float f) {
    unsigned u = __float_as_uint(f);
    unsigned r = (u + 0x7FFFu + ((u >> 16) & 1u)) >> 16;
    return (short)r;
}
DEV float bf2f(short h) {
    return __uint_as_float(((unsigned)(unsigned short)h) << 16);
}
DEV void split1(float f, short& h, short& l) {
    h = f2bf(f);
    l = f2bf(f - bf2f(h));
}

// ---------------------------------------------------------------------------
// One-shot weight conversion: fp32 -> bf16 hi + bf16 lo (same flat layout).
// Segment order / element offsets (elements):
//  fc1 0 | fc2 32768 | gru_wih 65536 | gru_whh 360448 | W_w 557056
//  ri 622592 | r1_wih 884736 | r1_whh 1933312 | r2_wih 2981888
//  r2_whh 4030464 | res_wih 5079040 | res_whh 11632640 | total 18186240
// ---------------------------------------------------------------------------
__global__ __launch_bounds__(256) void convert_w_kernel(
    const float* __restrict__ p0, const float* __restrict__ p1,
    const float* __restrict__ p2, const float* __restrict__ p3,
    const float* __restrict__ p4, const float* __restrict__ p5,
    const float* __restrict__ p6, const float* __restrict__ p7,
    const float* __restrict__ p8, const float* __restrict__ p9,
    const float* __restrict__ p10, const float* __restrict__ p11,
    short* __restrict__ hi, short* __restrict__ lo)
{
    // cumulative boundaries in float4 units
    const int c1 = 8192, c2 = 16384, c3 = 90112, c4 = 139264, c5 = 155648,
              c6 = 221184, c7 = 483328, c8 = 745472, c9 = 1007616,
              c10 = 1269760, c11 = 2908160, total = 4546560;
    for (int v = blockIdx.x * 256 + threadIdx.x; v < total; v += gridDim.x * 256) {
        const float* s = p0; int base = 0;
        if (v >= c1)  { s = p1;  base = c1; }
        if (v >= c2)  { s = p2;  base = c2; }
        if (v >= c3)  { s = p3;  base = c3; }
        if (v >= c4)  { s = p4;  base = c4; }
        if (v >= c5)  { s = p5;  base = c5; }
        if (v >= c6)  { s = p6;  base = c6; }
        if (v >= c7)  { s = p7;  base = c7; }
        if (v >= c8)  { s = p8;  base = c8; }
        if (v >= c9)  { s = p9;  base = c9; }
        if (v >= c10) { s = p10; base = c10; }
        if (v >= c11) { s = p11; base = c11; }
        float4 f = ((const float4*)s)[v - base];
        short4 h, l;
        split1(f.x, h.x, l.x);
        split1(f.y, h.y, l.y);
        split1(f.z, h.z, l.z);
        split1(f.w, h.w, l.w);
        ((short4*)hi)[v] = h;
        ((short4*)lo)[v] = l;
    }
}

// ---------------------------------------------------------------------------
// Split-K 2-segment MFMA GEMM, split-bf16 (hi/lo) for fp32-grade accuracy.
// A fp32 [128][K] row-major (split to bf16 hi/lo in-register);
// W pre-converted bf16 hi/lo, row-major [N][ldw].
// Out Cp[chunk][m=128][n]; block = 256 thr = 4 waves; 32-wide n-tile/block,
// wave w owns rows w*32..w*32+31 (2 m-tiles x 2 n-tiles of 16x16).
// Grid = (N/32)*KS; KC % 32 == 0; segment boundary K1 % 32 == 0.
// MFMA layout cloned from harness-verified attn_u usage:
//   D row (first-operand idx) = (lane>>4)*4+reg, D col (second) = lane&15,
//   operand k = (lane>>4)*8 + j.
// ---------------------------------------------------------------------------
__global__ __launch_bounds__(256) void gemm_mfma_kernel(
    const float* __restrict__ A1, int K1,
    const short* __restrict__ W1hi, const short* __restrict__ W1lo, int ldw1,
    const float* __restrict__ A2, int K2,
    const short* __restrict__ W2hi, const short* __restrict__ W2lo, int ldw2,
    float* __restrict__ Cp, int N, int KS, int KC)
{
    const int tid = threadIdx.x;
    const int chunk = blockIdx.x % KS;
    const int n0 = (blockIdx.x / KS) * 32;
    const int kbeg = chunk * KC;
    const int w = tid >> 6, lane = tid & 63;
    const int q = lane >> 4, r = lane & 15;
    const int m_base = w * 32;

    f32x4 acc[2][2];
#pragma unroll
    for (int mt = 0; mt < 2; ++mt)
#pragma unroll
        for (int nt = 0; nt < 2; ++nt)
            acc[mt][nt] = (f32x4){0.f, 0.f, 0.f, 0.f};

    auto load_frag = [&](int kg, float4 (&a)[2][2], short8 (&bh)[2], short8 (&bl)[2]) {
        const float* A; const short *Wh, *Wl; int lda, ldw, kc;
        if (kg < K1) { A = A1; Wh = W1hi; Wl = W1lo; lda = K1; ldw = ldw1; kc = kg; }
        else         { A = A2; Wh = W2hi; Wl = W2lo; lda = K2; ldw = ldw2; kc = kg - K1; }
        // A first so the hi/lo split can start while B loads are in flight
#pragma unroll
        for (int mt = 0; mt < 2; ++mt) {
            const float* ap = A + (size_t)(m_base + mt * 16 + r) * lda + kc + q * 8;
            a[mt][0] = *(const float4*)ap;
            a[mt][1] = *(const float4*)(ap + 4);
        }
#pragma unroll
        for (int nt = 0; nt < 2; ++nt) {
            size_t off = (size_t)(n0 + nt * 16 + r) * ldw + kc + q * 8;
            bh[nt] = *(const short8*)(Wh + off);
            bl[nt] = *(const short8*)(Wl + off);
        }
    };

    auto compute = [&](const float4 (&a)[2][2], const short8 (&bh)[2], const short8 (&bl)[2]) {
#pragma unroll
        for (int mt = 0; mt < 2; ++mt) {
            float fv[8] = {a[mt][0].x, a[mt][0].y, a[mt][0].z, a[mt][0].w,
                           a[mt][1].x, a[mt][1].y, a[mt][1].z, a[mt][1].w};
            short8 ah, al;
#pragma unroll
            for (int j = 0; j < 8; ++j) {
                short h, l;
                split1(fv[j], h, l);
                ah[j] = h; al[j] = l;
            }
#pragma unroll
            for (int nt = 0; nt < 2; ++nt) {
                acc[mt][nt] = __builtin_amdgcn_mfma_f32_16x16x32_bf16(ah, bh[nt], acc[mt][nt], 0, 0, 0);
                acc[mt][nt] = __builtin_amdgcn_mfma_f32_16x16x32_bf16(al, bh[nt], acc[mt][nt], 0, 0, 0);
                acc[mt][nt] = __builtin_amdgcn_mfma_f32_16x16x32_bf16(ah, bl[nt], acc[mt][nt], 0, 0, 0);
            }
        }
    };

    float4 a0[2][2], a1[2][2];
    short8 bh0[2], bl0[2], bh1[2], bl1[2];
    const int nsteps = KC >> 5;

    load_frag(kbeg, a0, bh0, bl0);
    for (int s = 0; s + 1 < nsteps; ++s) {
        if (s & 1) { load_frag(kbeg + (s + 1) * 32, a0, bh0, bl0); compute(a1, bh1, bl1); }
        else       { load_frag(kbeg + (s + 1) * 32, a1, bh1, bl1); compute(a0, bh0, bl0); }
    }
    if ((nsteps - 1) & 1) compute(a1, bh1, bl1);
    else                  compute(a0, bh0, bl0);

    float* Co = Cp + (size_t)chunk * 128 * N;
#pragma unroll
    for (int mt = 0; mt < 2; ++mt)
#pragma unroll
        for (int nt = 0; nt < 2; ++nt)
#pragma unroll
            for (int i = 0; i < 4; ++i)
                Co[(size_t)(m_base + mt * 16 + q * 4 + i) * N + n0 + nt * 16 + r] = acc[mt][nt][i];
}

// ---------------------------------------------------------------------------
__global__ void reduce_act_kernel(const float* __restrict__ p, int KS, int MN,
                                  const float* __restrict__ b,
                                  float* __restrict__ out, int N, int act)
{
    int idx = blockIdx.x * 256 + threadIdx.x;
    if (idx >= MN) return;
    int n = idx % N;
    float v = b ? b[n] : 0.f;
    for (int s = 0; s < KS; ++s) v += p[(size_t)s * MN + idx];
    if (act) v = tanhf_fast(v);
    out[idx] = v;
}

// ---------------------------------------------------------------------------
__global__ void gru_gate_kernel(const float* __restrict__ gi_p, int KSi,
                                const float* __restrict__ gh_p, int KSh,
                                const float* __restrict__ bih, const float* __restrict__ bhh,
                                const float* __restrict__ h, float* __restrict__ out)
{
    const size_t MN = 128 * 768;
    int m = blockIdx.x, d = threadIdx.x;
    size_t base = (size_t)m * 768 + d;
    float ir = bih[d], iz = bih[256 + d], in = bih[512 + d];
    for (int s = 0; s < KSi; ++s) {
        const float* p = gi_p + s * MN + base;
        ir += p[0]; iz += p[256]; in += p[512];
    }
    float hr = bhh[d], hz = bhh[256 + d], hn = bhh[512 + d];
    for (int s = 0; s < KSh; ++s) {
        const float* p = gh_p + s * MN + base;
        hr += p[0]; hz += p[256]; hn += p[512];
    }
    float r = sigm(ir + hr);
    float z = sigm(iz + hz);
    float n = tanhf_fast(in + r * hn);
    out[m * 256 + d] = (1.f - z) * n + z * h[m * 256 + d];
}

// ---------------------------------------------------------------------------
__global__ void lstm_gate_kernel(const float* __restrict__ gp, int KS,
                                 const float* __restrict__ bih, const float* __restrict__ bhh,
                                 const float* __restrict__ c_in,
                                 float* __restrict__ h_out, float* __restrict__ c_out,
                                 float* __restrict__ xacc, int H)
{
    int d = blockIdx.x * 256 + threadIdx.x;
    int m = blockIdx.y;
    if (d >= H) return;
    const size_t MN = (size_t)128 * 4 * H;
    size_t base = (size_t)m * 4 * H + d;
    float iv = bih[d] + bhh[d];
    float fv = bih[H + d] + bhh[H + d];
    float gv = bih[2 * H + d] + bhh[2 * H + d];
    float ov = bih[3 * H + d] + bhh[3 * H + d];
    for (int s = 0; s < KS; ++s) {
        const float* p = gp + s * MN + base;
        iv += p[0]; fv += p[H]; gv += p[2 * H]; ov += p[3 * H];
    }
    float c2 = sigm(fv) * c_in[m * H + d] + sigm(iv) * tanhf_fast(gv);
    float h2 = sigm(ov) * tanhf_fast(c2);
    h_out[m * H + d] = h2;
    c_out[m * H + d] = c2;
    if (xacc) xacc[m * H + d] += h2;
}

// ---------------------------------------------------------------------------
// L_w -> bf16 (row-major [d=256][c=32], same layout as source).  8192 elems.
// ---------------------------------------------------------------------------
__global__ void lw_bf16_kernel(const float* __restrict__ Lw, short* __restrict__ LwBf)
{
    int i = blockIdx.x * 256 + threadIdx.x;
    LwBf[i] = f2bf(Lw[i]);
}

// ---------------------------------------------------------------------------
// Fused LSA u-kernel: conv(loc) -> bf16 MFMA L-projection -> tanh -> v-dot ->
// sigmoid(u).  grid(B*16) blocks (64 t's each), 256 threads (4 waves).
// ---------------------------------------------------------------------------
__global__ __launch_bounds__(256) void attn_u_kernel(
    const float* __restrict__ esp, const float* __restrict__ pq,
    const short* __restrict__ LwBf, const float* __restrict__ Lb,
    const float* __restrict__ vw, const float* __restrict__ cw,
    const float* __restrict__ cum, const float* __restrict__ prev,
    float* __restrict__ sig_out)
{
    const int b = blockIdx.x >> 4;
    const int t0 = (blockIdx.x & 15) << 6;
    const int tid = threadIdx.x;

    __shared__ float cum_s[94], prev_s[94];
    __shared__ float cw_s[2][32][33];
    __shared__ short conv_bf[64 * 32];
    __shared__ short lw_bf[256 * 32];
    __shared__ float pq_s[256], vw_s[256];

    if (tid < 94) {
        int ti = t0 - 15 + tid;
        cum_s[tid] = (ti >= 0 && ti < 1024) ? cum[b * 1024 + ti] : 0.f;
    } else if (tid >= 128 && tid < 222) {
        int i = tid - 128;
        int ti = t0 - 15 + i;
        prev_s[i] = (ti >= 0 && ti < 1024) ? prev[b * 1024 + ti] : 0.f;
    }
    for (int i = tid; i < 2048; i += 256) {
        int which = i >> 10, c = (i >> 5) & 31, k = i & 31;
        cw_s[which][c][k] = (k < 31) ? cw[(c * 2 + which) * 31 + k] : 0.f;
    }
    {
        const int4* src = (const int4*)LwBf;
        int4* dst = (int4*)lw_bf;
#pragma unroll
        for (int k = 0; k < 4; ++k) dst[tid + k * 256] = src[tid + k * 256];
    }
    pq_s[tid] = pq[b * 256 + tid] + Lb[tid];
    vw_s[tid] = vw[tid];
    __syncthreads();

    {
        int c = tid & 31, t8 = (tid >> 5) << 3;
        float a[8] = {0.f, 0.f, 0.f, 0.f, 0.f, 0.f, 0.f, 0.f};
        for (int k = 0; k < 31; ++k) {
            float w0 = cw_s[0][c][k], w1 = cw_s[1][c][k];
#pragma unroll
            for (int j = 0; j < 8; ++j)
                a[j] += w0 * cum_s[t8 + j + k] + w1 * prev_s[t8 + j + k];
        }
#pragma unroll
        for (int j = 0; j < 8; ++j) conv_bf[(t8 + j) * 32 + c] = f2bf(a[j]);
    }
    __syncthreads();

    const int lane = tid & 63, w = tid >> 6;
    const int q = lane >> 4, c16 = lane & 15;
    const int myt = t0 + w * 16 + c16;

    short8 bfrag = *(const short8*)&conv_bf[(w * 16 + c16) * 32 + q * 8];
    const float* er = esp + ((size_t)(b * 1024 + myt) << 8);

    float s = 0.f;
#pragma unroll
    for (int dt = 0; dt < 16; ++dt) {
        short8 afrag = *(const short8*)&lw_bf[(dt * 16 + c16) * 32 + q * 8];
        f32x4 acc = {0.f, 0.f, 0.f, 0.f};
        acc = __builtin_amdgcn_mfma_f32_16x16x32_bf16(afrag, bfrag, acc, 0, 0, 0);
        const int d0 = dt * 16 + q * 4;
        float4 e   = *(const float4*)(er + d0);
        float4 pqv = *(const float4*)&pq_s[d0];
        float4 vwv = *(const float4*)&vw_s[d0];
        s += tanhf_fast(pqv.x + e.x + acc[0]) * vwv.x;
        s += tanhf_fast(pqv.y + e.y + acc[1]) * vwv.y;
        s += tanhf_fast(pqv.z + e.z + acc[2]) * vwv.z;
        s += tanhf_fast(pqv.w + e.w + acc[3]) * vwv.w;
    }
    s += __shfl_xor(s, 16);
    s += __shfl_xor(s, 32);
    if (lane < 16)
        sig_out[b * 1024 + t0 + w * 16 + lane] = sigm(s);
}

// ---------------------------------------------------------------------------
__global__ void attn_norm_kernel(const float* __restrict__ sig, const float* __restrict__ cum,
                                 float* __restrict__ scores, float* __restrict__ cum_new,
                                 float* __restrict__ ctx)
{
    __shared__ float red[4];
    int b = blockIdx.x, tid = threadIdx.x;
    float4 sv = *(const float4*)&sig[b * 1024 + tid * 4];
    float s = sv.x + sv.y + sv.z + sv.w;
#pragma unroll
    for (int off = 1; off < 64; off <<= 1) s += __shfl_xor(s, off);
    if ((tid & 63) == 0) red[tid >> 6] = s;
    __syncthreads();
    float inv = fast_rcp(red[0] + red[1] + red[2] + red[3]);
    float4 cv = *(const float4*)&cum[b * 1024 + tid * 4];
    float4 sc = {sv.x * inv, sv.y * inv, sv.z * inv, sv.w * inv};
    *(float4*)&scores[b * 1024 + tid * 4] = sc;
    float4 cn = {cv.x + sc.x, cv.y + sc.y, cv.z + sc.z, cv.w + sc.w};
    *(float4*)&cum_new[b * 1024 + tid * 4] = cn;
    ctx[b * 256 + tid] = 0.f;
}

// ---------------------------------------------------------------------------
__global__ void attn_ctx_kernel(const float* __restrict__ scores, const float* __restrict__ es,
                                float* __restrict__ ctx)
{
    __shared__ float sc_s[128];
    int b = blockIdx.x >> 3;
    int tbase = (blockIdx.x & 7) * 128;
    int tid = threadIdx.x;
    if (tid < 128) sc_s[tid] = scores[b * 1024 + tbase + tid];
    __syncthreads();
    float a = 0.f;
    const float* ep = es + ((size_t)(b * 1024 + tbase)) * 256 + tid;
#pragma unroll 4
    for (int tt = 0; tt < 128; ++tt)
        a += sc_s[tt] * ep[(size_t)tt * 256];
    atomicAdd(&ctx[b * 256 + tid], a);
}

// ---------------------------------------------------------------------------
__global__ void build_rescat_kernel(const float* __restrict__ pre, const float* __restrict__ x,
                                    float* __restrict__ res)
{
    int idx = blockIdx.x * 256 + threadIdx.x;
    int m = idx / 640, d = idx - m * 640;
    res[idx] = (d < 128) ? pre[m * 128 + d] : x[m * 512 + d - 128];
}

__global__ void copy_kernel(const float* __restrict__ src, float* __restrict__ dst, int n)
{
    int idx = blockIdx.x * 256 + threadIdx.x;
    if (idx < n) dst[idx] = src[idx];
}

__global__ void stop_kernel(const float* __restrict__ res, const float* __restrict__ sw,
                            const float* __restrict__ sb, float* __restrict__ stop)
{
    int m = blockIdx.x, lane = threadIdx.x;
    float s = 0.f;
    for (int k = lane; k < 640; k += 64) s += res[m * 640 + k] * sw[k];
#pragma unroll
    for (int off = 1; off < 64; off <<= 1) s += __shfl_xor(s, off);
    if (lane == 0) stop[m] = sigm(s + sb[0]);
}

// ---------------------------------------------------------------------------
extern "C" void kernel_launch(void* const* d_in, const int* in_sizes, int n_in,
                              void* d_out, int out_size, void* d_ws, size_t ws_size,
                              hipStream_t stream)
{
    const float* encoder_seq      = (const float*)d_in[0];
    const float* encoder_seq_proj = (const float*)d_in[1];
    const float* prenet_in        = (const float*)d_in[2];
    const float* attn_hidden      = (const float*)d_in[3];
    const float* rnn1_h  = (const float*)d_in[4];
    const float* rnn1_c  = (const float*)d_in[5];
    const float* rnn2_h  = (const float*)d_in[6];
    const float* rnn2_c  = (const float*)d_in[7];
    const float* res_h   = (const float*)d_in[8];
    const float* res_c   = (const float*)d_in[9];
    const float* context_vec = (const float*)d_in[10];
    const float* cumulative  = (const float*)d_in[11];
    const float* attn_prev   = (const float*)d_in[12];
    const float* fc1_w = (const float*)d_in[13];
    const float* fc1_b = (const float*)d_in[14];
    const float* fc2_w = (const float*)d_in[15];
    const float* fc2_b = (const float*)d_in[16];
    const float* gru_wih = (const float*)d_in[17];
    const float* gru_whh = (const float*)d_in[18];
    const float* gru_bih = (const float*)d_in[19];
    const float* gru_bhh = (const float*)d_in[20];
    const float* conv_w = (const float*)d_in[21];
    const float* L_w = (const float*)d_in[22];
    const float* L_b = (const float*)d_in[23];
    const float* W_w = (const float*)d_in[24];
    const float* W_b = (const float*)d_in[25];
    const float* v_w = (const float*)d_in[26];
    const float* ri_w = (const float*)d_in[27];
    const float* ri_b = (const float*)d_in[28];
    const float* r1_wih = (const float*)d_in[29];
    const float* r1_whh = (const float*)d_in[30];
    const float* r1_bih = (const float*)d_in[31];
    const float* r1_bhh = (const float*)d_in[32];
    const float* r2_wih = (const float*)d_in[33];
    const float* r2_whh = (const float*)d_in[34];
    const float* r2_bih = (const float*)d_in[35];
    const float* r2_bhh = (const float*)d_in[36];
    const float* res_wih = (const float*)d_in[37];
    const float* res_whh = (const float*)d_in[38];
    const float* res_bih = (const float*)d_in[39];
    const float* res_bhh = (const float*)d_in[40];
    const float* stop_w = (const float*)d_in[41];
    const float* stop_b = (const float*)d_in[42];

    float* ws  = (float*)d_ws;
    float* out = (float*)d_out;

    // workspace offsets (floats)
    const size_t OFF_P    = 0;        // [128,256]
    const size_t OFF_POUT = 32768;    // [128,128]
    const size_t OFF_PQ   = 49152;    // [128,256]
    const size_t OFF_SIG  = 81920;    // [128,1024]
    const size_t OFF_X    = 212992;   // [128,512]
    const size_t OFF_RES  = 278528;   // [128,640]
    const size_t OFF_LWT  = 360448;   // bf16 L_w (16 KB)
    const size_t OFF_PART = 368640;   // split-K partials (max 8*128*2560 fl)
    const size_t OFF_PARTB = OFF_PART + (size_t)12 * 128 * 768;
    const size_t OFF_WBF  = 4000000;  // bf16 split weights (hi then lo)

    // converted-weight element offsets (order matches convert_w_kernel)
    const size_t WOFF_FC1 = 0,        WOFF_FC2 = 32768,   WOFF_GI = 65536,
                 WOFF_GH  = 360448,   WOFF_WW  = 557056,  WOFF_RI = 622592,
                 WOFF_R1I = 884736,   WOFF_R1H = 1933312, WOFF_R2I = 2981888,
                 WOFF_R2H = 4030464,  WOFF_RESI = 5079040, WOFF_RESH = 11632640,
                 W_TOTAL  = 18186240;
    short* WHI = (short*)(ws + OFF_WBF);
    short* WLO = WHI + W_TOTAL;

    // output offsets (floats)
    const size_t O_COND   = 0;
    const size_t O_STOP   = 81920;
    const size_t O_SCORES = 82048;
    const size_t O_ATTNH  = 213120;
    const size_t O_H1     = 245888;
    const size_t O_C1     = 311424;
    const size_t O_H2     = 376960;
    const size_t O_C2     = 442496;
    const size_t O_HS     = 508032;
    const size_t O_CS     = 835712;
    const size_t O_CTX    = 1163392;
    const size_t O_CUM    = 1196160;

    // ---- weight conversion (one pass, independent of everything else) ----
    convert_w_kernel<<<2048, 256, 0, stream>>>(
        fc1_w, fc2_w, gru_wih, gru_whh, W_w, ri_w,
        r1_wih, r1_whh, r2_wih, r2_whh, res_wih, res_whh, WHI, WLO);

    short* lwbf = (short*)(ws + OFF_LWT);
    lw_bf16_kernel<<<32, 256, 0, stream>>>(L_w, lwbf);

    // PreNet fc1: N=256, K=128, KS=4 (KC=32)
    gemm_mfma_kernel<<<8 * 4, 256, 0, stream>>>(
        prenet_in, 128, WHI + WOFF_FC1, WLO + WOFF_FC1, 128,
        nullptr, 0, nullptr, nullptr, 0,
        ws + OFF_PART, 256, 4, 32);
    reduce_act_kernel<<<128, 256, 0, stream>>>(ws + OFF_PART, 4, 128 * 256, fc1_b,
                                               ws + OFF_P, 256, 1);
    // PreNet fc2: N=128, K=256, KS=8 (KC=32)
    gemm_mfma_kernel<<<4 * 8, 256, 0, stream>>>(
        ws + OFF_P, 256, WHI + WOFF_FC2, WLO + WOFF_FC2, 256,
        nullptr, 0, nullptr, nullptr, 0,
        ws + OFF_PART, 128, 8, 32);
    reduce_act_kernel<<<64, 256, 0, stream>>>(ws + OFF_PART, 8, 128 * 128, fc2_b,
                                              ws + OFF_POUT, 128, 1);

    // GRU gi: N=768, K=256+128, KS=12 (KC=32);  gh: N=768, K=256, KS=8 (KC=32)
    gemm_mfma_kernel<<<24 * 12, 256, 0, stream>>>(
        context_vec, 256, WHI + WOFF_GI, WLO + WOFF_GI, 384,
        ws + OFF_POUT, 128, WHI + WOFF_GI + 256, WLO + WOFF_GI + 256, 384,
        ws + OFF_PART, 768, 12, 32);
    gemm_mfma_kernel<<<24 * 8, 256, 0, stream>>>(
        attn_hidden, 256, WHI + WOFF_GH, WLO + WOFF_GH, 256,
        nullptr, 0, nullptr, nullptr, 0,
        ws + OFF_PARTB, 768, 8, 32);
    gru_gate_kernel<<<128, 256, 0, stream>>>(ws + OFF_PART, 12, ws + OFF_PARTB, 8,
                                             gru_bih, gru_bhh, attn_hidden, out + O_ATTNH);

    // pq: N=256, K=256, KS=8 (KC=32)
    gemm_mfma_kernel<<<8 * 8, 256, 0, stream>>>(
        out + O_ATTNH, 256, WHI + WOFF_WW, WLO + WOFF_WW, 256,
        nullptr, 0, nullptr, nullptr, 0,
        ws + OFF_PART, 256, 8, 32);
    reduce_act_kernel<<<128, 256, 0, stream>>>(ws + OFF_PART, 8, 128 * 256, W_b,
                                               ws + OFF_PQ, 256, 0);

    attn_u_kernel<<<2048, 256, 0, stream>>>(encoder_seq_proj, ws + OFF_PQ, lwbf,
                                            L_b, v_w, conv_w, cumulative, attn_prev,
                                            ws + OFF_SIG);
    attn_norm_kernel<<<128, 256, 0, stream>>>(ws + OFF_SIG, cumulative,
                                              out + O_SCORES, out + O_CUM, out + O_CTX);
    attn_ctx_kernel<<<1024, 256, 0, stream>>>(out + O_SCORES, encoder_seq, out + O_CTX);

    // x = [context | attn_h] @ ri_w^T + ri_b : N=512, K=512, KS=8 (KC=64)
    gemm_mfma_kernel<<<16 * 8, 256, 0, stream>>>(
        out + O_CTX, 256, WHI + WOFF_RI, WLO + WOFF_RI, 512,
        out + O_ATTNH, 256, WHI + WOFF_RI + 256, WLO + WOFF_RI + 256, 512,
        ws + OFF_PART, 512, 8, 64);
    reduce_act_kernel<<<256, 256, 0, stream>>>(ws + OFF_PART, 8, 128 * 512, ri_b,
                                               ws + OFF_X, 512, 0);

    // LSTM 1: N=2048, K=512+512, KS=8 (KC=128)
    gemm_mfma_kernel<<<64 * 8, 256, 0, stream>>>(
        ws + OFF_X, 512, WHI + WOFF_R1I, WLO + WOFF_R1I, 512,
        rnn1_h, 512, WHI + WOFF_R1H, WLO + WOFF_R1H, 512,
        ws + OFF_PART, 2048, 8, 128);
    lstm_gate_kernel<<<dim3(2, 128), 256, 0, stream>>>(ws + OFF_PART, 8, r1_bih, r1_bhh,
                                                       rnn1_c, out + O_H1, out + O_C1,
                                                       ws + OFF_X, 512);
    // LSTM 2
    gemm_mfma_kernel<<<64 * 8, 256, 0, stream>>>(
        ws + OFF_X, 512, WHI + WOFF_R2I, WLO + WOFF_R2I, 512,
        rnn2_h, 512, WHI + WOFF_R2H, WLO + WOFF_R2H, 512,
        ws + OFF_PART, 2048, 8, 128);
    lstm_gate_kernel<<<dim3(2, 128), 256, 0, stream>>>(ws + OFF_PART, 8, r2_bih, r2_bhh,
                                                       rnn2_c, out + O_H2, out + O_C2,
                                                       ws + OFF_X, 512);

    build_rescat_kernel<<<320, 256, 0, stream>>>(prenet_in, ws + OFF_X, ws + OFF_RES);

    // Residual stack: N=2560, K=640+640, KS=8 (KC=160)
    for (int i = 0; i < 4; ++i) {
        const short* wih_hi = WHI + WOFF_RESI + (size_t)i * 2560 * 640;
        const short* wih_lo = WLO + WOFF_RESI + (size_t)i * 2560 * 640;
        const short* whh_hi = WHI + WOFF_RESH + (size_t)i * 2560 * 640;
        const short* whh_lo = WLO + WOFF_RESH + (size_t)i * 2560 * 640;
        gemm_mfma_kernel<<<80 * 8, 256, 0, stream>>>(
            ws + OFF_RES, 640, wih_hi, wih_lo, 640,
            res_h + (size_t)i * 81920, 640, whh_hi, whh_lo, 640,
            ws + OFF_PART, 2560, 8, 160);
        lstm_gate_kernel<<<dim3(3, 128), 256, 0, stream>>>(ws + OFF_PART, 8,
                                                           res_bih + (size_t)i * 2560,
                                                           res_bhh + (size_t)i * 2560,
                                                           res_c + (size_t)i * 81920,
                                                           out + O_HS + (size_t)i * 81920,
                                                           out + O_CS + (size_t)i * 81920,
                                                           ws + OFF_RES, 640);
    }

    copy_kernel<<<320, 256, 0, stream>>>(ws + OFF_RES, out + O_COND, 128 * 640);
    stop_kernel<<<128, 64, 0, stream>>>(ws + OFF_RES, stop_w, stop_b, out + O_STOP);
}